// Round 5
// baseline (559.322 us; speedup 1.0000x reference)
//
#include <hip/hip_runtime.h>
#include <math.h>

namespace {

constexpr int Sq = 43;
constexpr int Dm = 18;
constexpr int Dff = 2048;
constexpr int Am = 128;
constexpr int Nb = 7;
constexpr int NR = 11008;          // B*SEQ rows
constexpr int RSZ = NR * Dm;       // 198144 floats
constexpr int WROW = 20;           // padded weight row (18 w + b1 + pad)
constexpr float EPSf = 1e-6f;

typedef float v2f __attribute__((ext_vector_type(2)));
typedef float v4f __attribute__((ext_vector_type(4)));

// ---------------------------------------------------------------------------
// k_attn: fused per-layer front half. (UNCHANGED from R4)
//   blocks 0..255   : batch b. Lane (<43) = query row.
//     y = X[row] (fully accumulated by previous layer's k_ffn atomics),
//     LN1 + QKV in-block (k/v -> LDS, q -> regs), attention, o-proj,
//     residual, Xn seed (+b2), LN2 -> x2g.
//   layer-0 extra blocks (grid 449):
//     256..447 : FFN weight prep (padded 20-float rows, transposed W1).
//     448      : tail precompute (Mw / PS1 / QS2) for k_out.
// ---------------------------------------------------------------------------
__global__ __launch_bounds__(64) void k_attn(
    int layer,
    const float* __restrict__ Xi, float* __restrict__ Xn,
    float* __restrict__ x2g,
    const int* __restrict__ maskg,
    const float* __restrict__ Wq, const float* __restrict__ bq,
    const float* __restrict__ Wk, const float* __restrict__ bk,
    const float* __restrict__ Wv, const float* __restrict__ bv,
    const float* __restrict__ ln1a, const float* __restrict__ ln1b,
    const float* __restrict__ Wo, const float* __restrict__ bo,
    const float* __restrict__ ln2a, const float* __restrict__ ln2b,
    const float* __restrict__ b2g,
    const float* __restrict__ fW1g, const float* __restrict__ fb1g,
    const float* __restrict__ fW2g,
    float* __restrict__ W1P, float* __restrict__ W2P,
    const float* __restrict__ llW, const float* __restrict__ llb,
    const float* __restrict__ flW, const float* __restrict__ flb,
    const float* __restrict__ ll2b,
    float* __restrict__ Mw, float* __restrict__ PS1, float* __restrict__ QS2)
{
    __shared__ __align__(16) float ks[Sq * 20];
    __shared__ __align__(16) float vs[Sq * 20];
    __shared__ int ms[Sq];
    __shared__ float M[602];
    __shared__ float cc2[14];
    __shared__ float SS[14];

    const int tid = threadIdx.x;
    const int b = blockIdx.x;

    if (b >= 256) {                       // layer-0 auxiliary blocks only
        if (b < 448) {
            // ---- FFN weight prep (64-thread version of old k_wprep) ----
            const int idx = (b - 256) * 64 + tid;      // 0..12287
            const int l = idx / Dff;
            const int j = idx - l * Dff;
            float* o1 = W1P + (size_t)idx * WROW;
            float* o2 = W2P + (size_t)idx * WROW;
            #pragma unroll
            for (int d = 0; d < Dm; d++)
                o1[d] = fW1g[(size_t)l * Dm * Dff + (size_t)d * Dff + j];
            o1[18] = fb1g[l * Dff + j];
            o1[19] = 0.f;
            #pragma unroll
            for (int d = 0; d < Dm; d++)
                o2[d] = fW2g[((size_t)l * Dff + j) * Dm + d];
            o2[18] = 0.f;
            o2[19] = 0.f;
            if (idx < WROW) {             // zero pad row (safety guard)
                W1P[(size_t)6 * Dff * WROW + idx] = 0.f;
                W2P[(size_t)6 * Dff * WROW + idx] = 0.f;
            }
            return;
        }
        // ---- b == 448: tail precompute (Mw / PS1 / QS2) ----
        for (int m = tid; m < 602; m += 64) {
            int half = m / 301, rem = m - half * 301;
            int s = rem / 7, n = rem - 7 * s;
            float a = 0.f;
            for (int jj = 0; jj < Am; jj++)
                a += llW[s * Am + jj] * flW[(half * Am + jj) * Nb + n];
            M[m] = a;
        }
        if (tid < 14) {
            int half = tid / 7, n = tid - 7 * (tid / 7);
            float a = 0.f;
            for (int jj = 0; jj < Am; jj++)
                a += llb[jj] * flW[(half * Am + jj) * Nb + n];
            cc2[tid] = a;
        }
        __syncthreads();
        if (tid < 14) {
            int half = tid / 7, n = tid - 7 * (tid / 7);
            float s2 = 0.f;
            for (int s = 0; s < Sq; s++) s2 += M[half * 301 + s * 7 + n];
            SS[tid] = s2;
        }
        __syncthreads();
        for (int m = tid; m < 602; m += 64) Mw[m] = M[m];
        for (int m = tid; m < 896; m += 64) {
            int i = m / 7, n = m - 7 * i;
            PS1[m] = cc2[n] + ll2b[i] * SS[n];
            QS2[m] = cc2[7 + n] + ll2b[i] * SS[7 + n] + flb[n];
        }
        return;
    }

    // -------------------- main path: one batch per block --------------------
    const float scale = 0.40824829046386296f;  // 1/sqrt(6)

    if (tid < Sq) ms[tid] = maskg[b * Sq + tid];

    float y[Dm];
    float qv[Dm];
    if (tid < Sq) {
        const size_t ro = (size_t)(b * Sq + tid) * Dm;
        // x row fully accumulated (prev layer's k_ffn atomics); float2 loads
        #pragma unroll
        for (int k = 0; k < 9; k++) {
            float2 t = *(const float2*)(Xi + ro + 2 * k);
            y[2 * k] = t.x; y[2 * k + 1] = t.y;
        }
        // LN1
        float mu = 0.f;
        #pragma unroll
        for (int d = 0; d < Dm; d++) mu += y[d];
        mu *= (1.f / Dm);
        float var = 0.f;
        #pragma unroll
        for (int d = 0; d < Dm; d++) { float t = y[d] - mu; var += t * t; }
        var *= (1.f / (Dm - 1));                 // ddof=1
        float isd = 1.f / (sqrtf(var) + EPSf);   // eps on sd
        float x2[Dm];
        #pragma unroll
        for (int d = 0; d < Dm; d++)
            x2[d] = ln1a[layer * Dm + d] * (y[d] - mu) * isd
                  + ln1b[layer * Dm + d];
        // QKV: q stays in registers, k/v go straight to LDS
        const float* wqp = Wq + layer * Dm * Dm;
        const float* wkp = Wk + layer * Dm * Dm;
        const float* wvp = Wv + layer * Dm * Dm;
        #pragma unroll 3
        for (int d = 0; d < Dm; d++) {
            float aq = bq[layer * Dm + d];
            float ak = bk[layer * Dm + d];
            float av = bv[layer * Dm + d];
            #pragma unroll
            for (int dd = 0; dd < Dm; dd++) {
                aq += x2[dd] * wqp[dd * Dm + d];
                ak += x2[dd] * wkp[dd * Dm + d];
                av += x2[dd] * wvp[dd * Dm + d];
            }
            qv[d] = aq;
            ks[tid * 20 + d] = ak;
            vs[tid * 20 + d] = av;
        }
    }
    __syncthreads();
    if (tid >= Sq) return;

    // attention: all 3 heads per lane (one-pass softmax, scores O(0.3))
    float o[Dm];
    #pragma unroll
    for (int h = 0; h < 3; h++) {
        float sum = 0.f;
        float o6[6];
        #pragma unroll
        for (int d = 0; d < 6; d++) o6[d] = 0.f;
        const float q0 = qv[h * 6], q1 = qv[h * 6 + 1], q2 = qv[h * 6 + 2];
        const float q3 = qv[h * 6 + 3], q4 = qv[h * 6 + 4], q5 = qv[h * 6 + 5];
        for (int j = 0; j < Sq; j++) {
            const float* kr = ks + j * 20 + h * 6;   // 8B-aligned
            const float2 k0 = *(const float2*)(kr);
            const float2 k1 = *(const float2*)(kr + 2);
            const float2 k2 = *(const float2*)(kr + 4);
            float t = q0 * k0.x + q1 * k0.y + q2 * k1.x +
                      q3 * k1.y + q4 * k2.x + q5 * k2.y;
            t *= scale;
            if (ms[j] == 0) t = -1e9f;
            float e = __expf(t);
            sum += e;
            const float* vr = vs + j * 20 + h * 6;
            const float2 v0 = *(const float2*)(vr);
            const float2 v1 = *(const float2*)(vr + 2);
            const float2 v2 = *(const float2*)(vr + 4);
            o6[0] += e * v0.x; o6[1] += e * v0.y; o6[2] += e * v1.x;
            o6[3] += e * v1.y; o6[4] += e * v2.x; o6[5] += e * v2.y;
        }
        float inv = 1.f / sum;
        #pragma unroll
        for (int d = 0; d < 6; d++) o[h * 6 + d] = o6[d] * inv;
    }

    // o-proj + residual + next-x seed + LN2 (all in-thread)
    const float* wo = Wo + layer * Dm * Dm;
    float yo[Dm];
    #pragma unroll 3
    for (int d = 0; d < Dm; d++) {
        float t = bo[layer * Dm + d];
        #pragma unroll
        for (int dd = 0; dd < Dm; dd++) t += o[dd] * wo[dd * Dm + d];
        yo[d] = y[d] + t;
    }
    const size_t ro = (size_t)(b * Sq + tid) * Dm;
    #pragma unroll
    for (int d = 0; d < Dm; d++)
        Xn[ro + d] = yo[d] + b2g[layer * Dm + d];   // seed: FFN atomics add here
    float mu = 0.f;
    #pragma unroll
    for (int d = 0; d < Dm; d++) mu += yo[d];
    mu *= (1.f / Dm);
    float var = 0.f;
    #pragma unroll
    for (int d = 0; d < Dm; d++) { float t = yo[d] - mu; var += t * t; }
    var *= (1.f / (Dm - 1));
    float isd = 1.f / (sqrtf(var) + EPSf);
    #pragma unroll
    for (int d = 0; d < Dm; d++)
        x2g[ro + d] =
            ln2a[layer * Dm + d] * (yo[d] - mu) * isd + ln2b[layer * Dm + d];
}

// ---------------------------------------------------------------------------
// k_ffn: LDS-staged weights (R5). Diagnosis: R1-R4 deltas show the inner
// loop was VMEM-LATENCY-bound (per-jj broadcast loads thrash L1 across the
// 3 resident q-slices; 1-deep prefetch + 3 waves/SIMD can't hide ~200cyc L2).
// Fix: each wave copies its whole 64-j slice (1280+1280 floats) to a private
// LDS region ONCE via 10 coalesced b128 loads, then the j-loop reads weights
// as LDS broadcasts (wave-uniform addr, ~2-4cyc, low latency). VMEM instr
// count drops 64x. Dropping the 80-VGPR global prefetch frees registers:
// launch_bounds(256,4) + exactly 40KB LDS/block -> 4 blocks/CU (16 waves).
// Reduce buffer aliases the dead weight LDS after a barrier. Same bits,
// same math as R4 -> absmax must stay 0.001953125. Atomic accumulate into
// Xn unchanged.
// ---------------------------------------------------------------------------
__global__ __launch_bounds__(256, 4) void k_ffn(
    int layer, const float* __restrict__ x2g,
    const float* __restrict__ W1P, const float* __restrict__ W2P,
    float* __restrict__ Xn)
{
    // 4 waves x (w1 slice 1280 | w2 slice 1280) floats = 40960 B exactly.
    // (Do NOT pad: 4 blocks x 40KB == 160KB LDS/CU capacity.)
    __shared__ __align__(16) float wbuf[10240];

    const int tid  = threadIdx.x;
    const int lane = tid & 63;
    const int wv   = __builtin_amdgcn_readfirstlane(tid >> 6);
    const int rg   = blockIdx.x >> 3;     // 0..171
    const int q    = blockIdx.x & 7;      // 0..7
    const int row  = rg * 64 + lane;
    const int j0   = q * 256 + wv * 64;

    // ---- one-shot stage: this wave's 64-j weight slice -> private LDS ----
    {
        const v4f* g1 = (const v4f*)(W1P + ((size_t)layer * Dff + j0) * WROW);
        const v4f* g2 = (const v4f*)(W2P + ((size_t)layer * Dff + j0) * WROW);
        v4f* s1 = (v4f*)(wbuf + wv * 2560);
        v4f* s2 = (v4f*)(wbuf + wv * 2560 + 1280);
        #pragma unroll
        for (int k = 0; k < 5; k++) s1[64 * k + lane] = g1[64 * k + lane];
        #pragma unroll
        for (int k = 0; k < 5; k++) s2[64 * k + lane] = g2[64 * k + lane];
    }
    // no barrier needed: each wave reads only its own region (wave-internal
    // LDS dependency; compiler orders via lgkmcnt).

    v2f xp[9];
    #pragma unroll
    for (int k = 0; k < 9; k++)
        xp[k] = *(const v2f*)(x2g + (size_t)row * Dm + 2 * k);

    v2f acc2[9];
    #pragma unroll
    for (int k = 0; k < 9; k++) acc2[k] = (v2f){0.f, 0.f};

    const float* wb1 = wbuf + wv * 2560;
    const float* wb2 = wbuf + wv * 2560 + 1280;

    #pragma unroll 2
    for (int jj = 0; jj < 64; jj++) {
        const v4f* w1r = (const v4f*)(wb1 + jj * 20);   // 80B rows, 16B-aligned
        const v4f* w2r = (const v4f*)(wb2 + jj * 20);
        const v4f a0 = w1r[0], a1 = w1r[1], a2 = w1r[2], a3 = w1r[3], a4 = w1r[4];
        const v4f c0 = w2r[0], c1 = w2r[1], c2 = w2r[2], c3 = w2r[3], c4 = w2r[4];

        // h: two 9-term packed chains (even d in .x, odd d in .y)
        v2f h2 = xp[0] * a0.lo;
        h2 = __builtin_elementwise_fma(xp[1], a0.hi, h2);
        h2 = __builtin_elementwise_fma(xp[2], a1.lo, h2);
        h2 = __builtin_elementwise_fma(xp[3], a1.hi, h2);
        h2 = __builtin_elementwise_fma(xp[4], a2.lo, h2);
        h2 = __builtin_elementwise_fma(xp[5], a2.hi, h2);
        h2 = __builtin_elementwise_fma(xp[6], a3.lo, h2);
        h2 = __builtin_elementwise_fma(xp[7], a3.hi, h2);
        h2 = __builtin_elementwise_fma(xp[8], a4.lo, h2);
        float h = a4.z + h2.x + h2.y;              // b1 in slot 18
        h = fmaxf(h, 0.f);
        const v2f hh = {h, h};

        acc2[0] = __builtin_elementwise_fma(hh, c0.lo, acc2[0]);
        acc2[1] = __builtin_elementwise_fma(hh, c0.hi, acc2[1]);
        acc2[2] = __builtin_elementwise_fma(hh, c1.lo, acc2[2]);
        acc2[3] = __builtin_elementwise_fma(hh, c1.hi, acc2[3]);
        acc2[4] = __builtin_elementwise_fma(hh, c2.lo, acc2[4]);
        acc2[5] = __builtin_elementwise_fma(hh, c2.hi, acc2[5]);
        acc2[6] = __builtin_elementwise_fma(hh, c3.lo, acc2[6]);
        acc2[7] = __builtin_elementwise_fma(hh, c3.hi, acc2[7]);
        acc2[8] = __builtin_elementwise_fma(hh, c4.lo, acc2[8]);
    }

    // ---- cross-wave reduce: alias the (now dead) weight LDS ----
    __syncthreads();                      // all waves done reading weights
    #pragma unroll
    for (int k = 0; k < 9; k++) {
        wbuf[(wv * 64 + lane) * Dm + 2 * k]     = acc2[k].x;
        wbuf[(wv * 64 + lane) * Dm + 2 * k + 1] = acc2[k].y;
    }
    __syncthreads();
    for (int e = tid; e < 1152; e += 256) {
        float s = wbuf[e] + wbuf[1152 + e] + wbuf[2304 + e] + wbuf[3456 + e];
        unsafeAtomicAdd(&Xn[(size_t)rg * 1152 + e], s);
    }
}

// ---------------------------------------------------------------------------
// k_out: (i-chunk, batch) blocks; float4 stores of the 117 MB output.
// Final x is fully accumulated in xg (layer-5 k_ffn atomics) -> plain read.
// (UNCHANGED from R4)
// ---------------------------------------------------------------------------
__global__ __launch_bounds__(256) void k_out(
    const float* __restrict__ xg,
    const float* __restrict__ ll2W,
    const float* __restrict__ Mw, const float* __restrict__ PS1,
    const float* __restrict__ QS2, float* __restrict__ out)
{
    __shared__ float xb[Sq * Dm];
    __shared__ float M[602];
    __shared__ float T[2][Dm][Nb];
    __shared__ float Pc[32 * Nb];
    __shared__ float QBs[Am * Nb];

    const int b = blockIdx.y, chunk = blockIdx.x, tid = threadIdx.x;

    for (int e = tid; e < Sq * Dm; e += 256)
        xb[e] = xg[(size_t)b * (Sq * Dm) + e];
    for (int m = tid; m < 602; m += 256) M[m] = Mw[m];
    __syncthreads();

    for (int m = tid; m < 252; m += 256) {
        int half = m / 126, rem = m - half * 126;
        int d = rem / 7, n = rem - 7 * d;
        float a = 0.f;
        for (int s = 0; s < Sq; s++)
            a += xb[s * Dm + d] * M[half * 301 + s * 7 + n];
        T[half][d][n] = a;
    }
    __syncthreads();

    for (int m = tid; m < 224; m += 256) {
        int il = m / 7, n = m - 7 * il;
        int i = chunk * 32 + il;
        float a = PS1[i * 7 + n];
        #pragma unroll
        for (int d = 0; d < Dm; d++) a += T[0][d][n] * ll2W[d * Am + i];
        Pc[m] = a;
    }
    for (int e = tid; e < 896; e += 256) {
        int jj = e / 7, n = e - 7 * jj;
        float a = QS2[e];
        #pragma unroll
        for (int d = 0; d < Dm; d++) a += T[1][d][n] * ll2W[d * Am + jj];
        QBs[e] = a;
    }
    __syncthreads();

    if (tid < 224) {
        const int e = 4 * tid;
        const float q0 = QBs[e], q1 = QBs[e + 1], q2 = QBs[e + 2], q3 = QBs[e + 3];
        const int n0 = e % 7, n1 = (e + 1) % 7, n2 = (e + 2) % 7, n3 = (e + 3) % 7;
        const size_t base = (size_t)b * (Am * Am * Nb)
                          + (size_t)chunk * 32 * 896 + e;
        for (int il = 0; il < 32; il++) {
            const float* pc = Pc + il * 7;
            float4 v;
            v.x = pc[n0] + q0; v.y = pc[n1] + q1;
            v.z = pc[n2] + q2; v.w = pc[n3] + q3;
            *(float4*)(out + base + (size_t)il * 896) = v;
        }
    }
}

} // namespace

// ---------------------------------------------------------------------------
extern "C" void kernel_launch(void* const* d_in, const int* in_sizes, int n_in,
                              void* d_out, int out_size, void* d_ws, size_t ws_size,
                              hipStream_t stream)
{
    (void)in_sizes; (void)n_in; (void)out_size; (void)ws_size;

    const float* src  = (const float*)d_in[0];
    const int*   mask = (const int*)  d_in[1];
    const float* Wq   = (const float*)d_in[3];
    const float* bq   = (const float*)d_in[4];
    const float* Wk   = (const float*)d_in[5];
    const float* bk   = (const float*)d_in[6];
    const float* Wv   = (const float*)d_in[7];
    const float* bv   = (const float*)d_in[8];
    const float* Wo   = (const float*)d_in[9];
    const float* bo   = (const float*)d_in[10];
    const float* ln1a = (const float*)d_in[11];
    const float* ln1b = (const float*)d_in[12];
    const float* ln2a = (const float*)d_in[13];
    const float* ln2b = (const float*)d_in[14];
    const float* fW1  = (const float*)d_in[15];
    const float* fb1  = (const float*)d_in[16];
    const float* fW2  = (const float*)d_in[17];
    const float* fb2  = (const float*)d_in[18];
    const float* ll2W = (const float*)d_in[19];
    const float* ll2b = (const float*)d_in[20];
    const float* llW  = (const float*)d_in[21];
    const float* llb  = (const float*)d_in[22];
    const float* flW  = (const float*)d_in[23];
    const float* flb  = (const float*)d_in[24];
    float* out = (float*)d_out;

    const size_t WPSZ = (size_t)6 * Dff * WROW + WROW;   // 245780

    float* ws  = (float*)d_ws;
    float* xA  = ws;
    float* xB  = ws + 1 * (size_t)RSZ;
    float* x2g = ws + 2 * (size_t)RSZ;
    float* W1P = ws + 3 * (size_t)RSZ;
    float* W2P = W1P + WPSZ;
    float* Mw  = W2P + WPSZ;                  // 602 (pad 604)
    float* PS1 = Mw + 604;
    float* QS2 = PS1 + 896;                   // total ~4.4 MB

    for (int i = 0; i < 6; i++) {
        const float* Xi = (i == 0) ? src : ((i % 2 == 1) ? xB : xA);
        float*       Xn = (i % 2 == 0) ? xB : xA;
        const int nblk = (i == 0) ? 449 : 256;   // layer 0 carries prep blocks
        k_attn<<<nblk, 64, 0, stream>>>(i, Xi, Xn, x2g, mask,
                                        Wq, bq, Wk, bk, Wv, bv,
                                        ln1a, ln1b, Wo, bo, ln2a, ln2b, fb2,
                                        fW1, fb1, fW2, W1P, W2P,
                                        llW, llb, flW, flb, ll2b,
                                        Mw, PS1, QS2);
        k_ffn<<<1376, 256, 0, stream>>>(i, x2g, W1P, W2P, Xn);
    }
    k_out<<<dim3(4, 256), 256, 0, stream>>>(xA, ll2W, Mw, PS1, QS2, out);
}

// Round 6
// 524.115 us; speedup vs baseline: 1.0672x; 1.0672x over previous
//
#include <hip/hip_runtime.h>
#include <math.h>

namespace {

constexpr int Sq = 43;
constexpr int Dm = 18;
constexpr int Dff = 2048;
constexpr int Am = 128;
constexpr int Nb = 7;
constexpr int NR = 11008;          // B*SEQ rows
constexpr int RSZ = NR * Dm;       // 198144 floats
constexpr int WROW = 20;           // padded weight row (18 w + b1 + pad)
constexpr float EPSf = 1e-6f;

typedef float v2f __attribute__((ext_vector_type(2)));
typedef float v4f __attribute__((ext_vector_type(4)));

// ---------------------------------------------------------------------------
// k_attn: fused per-layer front half. (UNCHANGED from R4)
//   blocks 0..255   : batch b. Lane (<43) = query row.
//     y = X[row] (fully accumulated by previous layer's k_ffn atomics),
//     LN1 + QKV in-block (k/v -> LDS, q -> regs), attention, o-proj,
//     residual, Xn seed (+b2), LN2 -> x2g.
//   layer-0 extra blocks (grid 449):
//     256..447 : FFN weight prep (padded 20-float rows, transposed W1).
//     448      : tail precompute (Mw / PS1 / QS2) for k_out.
// ---------------------------------------------------------------------------
__global__ __launch_bounds__(64) void k_attn(
    int layer,
    const float* __restrict__ Xi, float* __restrict__ Xn,
    float* __restrict__ x2g,
    const int* __restrict__ maskg,
    const float* __restrict__ Wq, const float* __restrict__ bq,
    const float* __restrict__ Wk, const float* __restrict__ bk,
    const float* __restrict__ Wv, const float* __restrict__ bv,
    const float* __restrict__ ln1a, const float* __restrict__ ln1b,
    const float* __restrict__ Wo, const float* __restrict__ bo,
    const float* __restrict__ ln2a, const float* __restrict__ ln2b,
    const float* __restrict__ b2g,
    const float* __restrict__ fW1g, const float* __restrict__ fb1g,
    const float* __restrict__ fW2g,
    float* __restrict__ W1P, float* __restrict__ W2P,
    const float* __restrict__ llW, const float* __restrict__ llb,
    const float* __restrict__ flW, const float* __restrict__ flb,
    const float* __restrict__ ll2b,
    float* __restrict__ Mw, float* __restrict__ PS1, float* __restrict__ QS2)
{
    __shared__ __align__(16) float ks[Sq * 20];
    __shared__ __align__(16) float vs[Sq * 20];
    __shared__ int ms[Sq];
    __shared__ float M[602];
    __shared__ float cc2[14];
    __shared__ float SS[14];

    const int tid = threadIdx.x;
    const int b = blockIdx.x;

    if (b >= 256) {                       // layer-0 auxiliary blocks only
        if (b < 448) {
            // ---- FFN weight prep (64-thread version of old k_wprep) ----
            const int idx = (b - 256) * 64 + tid;      // 0..12287
            const int l = idx / Dff;
            const int j = idx - l * Dff;
            float* o1 = W1P + (size_t)idx * WROW;
            float* o2 = W2P + (size_t)idx * WROW;
            #pragma unroll
            for (int d = 0; d < Dm; d++)
                o1[d] = fW1g[(size_t)l * Dm * Dff + (size_t)d * Dff + j];
            o1[18] = fb1g[l * Dff + j];
            o1[19] = 0.f;
            #pragma unroll
            for (int d = 0; d < Dm; d++)
                o2[d] = fW2g[((size_t)l * Dff + j) * Dm + d];
            o2[18] = 0.f;
            o2[19] = 0.f;
            if (idx < WROW) {             // zero pad row (safety guard)
                W1P[(size_t)6 * Dff * WROW + idx] = 0.f;
                W2P[(size_t)6 * Dff * WROW + idx] = 0.f;
            }
            return;
        }
        // ---- b == 448: tail precompute (Mw / PS1 / QS2) ----
        for (int m = tid; m < 602; m += 64) {
            int half = m / 301, rem = m - half * 301;
            int s = rem / 7, n = rem - 7 * s;
            float a = 0.f;
            for (int jj = 0; jj < Am; jj++)
                a += llW[s * Am + jj] * flW[(half * Am + jj) * Nb + n];
            M[m] = a;
        }
        if (tid < 14) {
            int half = tid / 7, n = tid - 7 * (tid / 7);
            float a = 0.f;
            for (int jj = 0; jj < Am; jj++)
                a += llb[jj] * flW[(half * Am + jj) * Nb + n];
            cc2[tid] = a;
        }
        __syncthreads();
        if (tid < 14) {
            int half = tid / 7, n = tid - 7 * (tid / 7);
            float s2 = 0.f;
            for (int s = 0; s < Sq; s++) s2 += M[half * 301 + s * 7 + n];
            SS[tid] = s2;
        }
        __syncthreads();
        for (int m = tid; m < 602; m += 64) Mw[m] = M[m];
        for (int m = tid; m < 896; m += 64) {
            int i = m / 7, n = m - 7 * i;
            PS1[m] = cc2[n] + ll2b[i] * SS[n];
            QS2[m] = cc2[7 + n] + ll2b[i] * SS[7 + n] + flb[n];
        }
        return;
    }

    // -------------------- main path: one batch per block --------------------
    const float scale = 0.40824829046386296f;  // 1/sqrt(6)

    if (tid < Sq) ms[tid] = maskg[b * Sq + tid];

    float y[Dm];
    float qv[Dm];
    if (tid < Sq) {
        const size_t ro = (size_t)(b * Sq + tid) * Dm;
        // x row fully accumulated (prev layer's k_ffn atomics); float2 loads
        #pragma unroll
        for (int k = 0; k < 9; k++) {
            float2 t = *(const float2*)(Xi + ro + 2 * k);
            y[2 * k] = t.x; y[2 * k + 1] = t.y;
        }
        // LN1
        float mu = 0.f;
        #pragma unroll
        for (int d = 0; d < Dm; d++) mu += y[d];
        mu *= (1.f / Dm);
        float var = 0.f;
        #pragma unroll
        for (int d = 0; d < Dm; d++) { float t = y[d] - mu; var += t * t; }
        var *= (1.f / (Dm - 1));                 // ddof=1
        float isd = 1.f / (sqrtf(var) + EPSf);   // eps on sd
        float x2[Dm];
        #pragma unroll
        for (int d = 0; d < Dm; d++)
            x2[d] = ln1a[layer * Dm + d] * (y[d] - mu) * isd
                  + ln1b[layer * Dm + d];
        // QKV: q stays in registers, k/v go straight to LDS
        const float* wqp = Wq + layer * Dm * Dm;
        const float* wkp = Wk + layer * Dm * Dm;
        const float* wvp = Wv + layer * Dm * Dm;
        #pragma unroll 3
        for (int d = 0; d < Dm; d++) {
            float aq = bq[layer * Dm + d];
            float ak = bk[layer * Dm + d];
            float av = bv[layer * Dm + d];
            #pragma unroll
            for (int dd = 0; dd < Dm; dd++) {
                aq += x2[dd] * wqp[dd * Dm + d];
                ak += x2[dd] * wkp[dd * Dm + d];
                av += x2[dd] * wvp[dd * Dm + d];
            }
            qv[d] = aq;
            ks[tid * 20 + d] = ak;
            vs[tid * 20 + d] = av;
        }
    }
    __syncthreads();
    if (tid >= Sq) return;

    // attention: all 3 heads per lane (one-pass softmax, scores O(0.3))
    float o[Dm];
    #pragma unroll
    for (int h = 0; h < 3; h++) {
        float sum = 0.f;
        float o6[6];
        #pragma unroll
        for (int d = 0; d < 6; d++) o6[d] = 0.f;
        const float q0 = qv[h * 6], q1 = qv[h * 6 + 1], q2 = qv[h * 6 + 2];
        const float q3 = qv[h * 6 + 3], q4 = qv[h * 6 + 4], q5 = qv[h * 6 + 5];
        for (int j = 0; j < Sq; j++) {
            const float* kr = ks + j * 20 + h * 6;   // 8B-aligned
            const float2 k0 = *(const float2*)(kr);
            const float2 k1 = *(const float2*)(kr + 2);
            const float2 k2 = *(const float2*)(kr + 4);
            float t = q0 * k0.x + q1 * k0.y + q2 * k1.x +
                      q3 * k1.y + q4 * k2.x + q5 * k2.y;
            t *= scale;
            if (ms[j] == 0) t = -1e9f;
            float e = __expf(t);
            sum += e;
            const float* vr = vs + j * 20 + h * 6;
            const float2 v0 = *(const float2*)(vr);
            const float2 v1 = *(const float2*)(vr + 2);
            const float2 v2 = *(const float2*)(vr + 4);
            o6[0] += e * v0.x; o6[1] += e * v0.y; o6[2] += e * v1.x;
            o6[3] += e * v1.y; o6[4] += e * v2.x; o6[5] += e * v2.y;
        }
        float inv = 1.f / sum;
        #pragma unroll
        for (int d = 0; d < 6; d++) o[h * 6 + d] = o6[d] * inv;
    }

    // o-proj + residual + next-x seed + LN2 (all in-thread)
    const float* wo = Wo + layer * Dm * Dm;
    float yo[Dm];
    #pragma unroll 3
    for (int d = 0; d < Dm; d++) {
        float t = bo[layer * Dm + d];
        #pragma unroll
        for (int dd = 0; dd < Dm; dd++) t += o[dd] * wo[dd * Dm + d];
        yo[d] = y[d] + t;
    }
    const size_t ro = (size_t)(b * Sq + tid) * Dm;
    #pragma unroll
    for (int d = 0; d < Dm; d++)
        Xn[ro + d] = yo[d] + b2g[layer * Dm + d];   // seed: FFN atomics add here
    float mu = 0.f;
    #pragma unroll
    for (int d = 0; d < Dm; d++) mu += yo[d];
    mu *= (1.f / Dm);
    float var = 0.f;
    #pragma unroll
    for (int d = 0; d < Dm; d++) { float t = yo[d] - mu; var += t * t; }
    var *= (1.f / (Dm - 1));
    float isd = 1.f / (sqrtf(var) + EPSf);
    #pragma unroll
    for (int d = 0; d < Dm; d++)
        x2g[ro + d] =
            ln2a[layer * Dm + d] * (yo[d] - mu) * isd + ln2b[layer * Dm + d];
}

// ---------------------------------------------------------------------------
// k_ffn (R6): revert R5's LDS staging (regressed: ds_read_b128 occupies the
// LDS pipe longer than the compute it feeds). Back to R4's direct
// wave-uniform weight loads + packed fp32, with ONE change: 2 ROWS PER
// THREAD sharing the same weight registers. Per jj the 10 loads are
// unchanged but packed FMAs double (23 -> 46) => compute/load ratio 2x,
// exposed weight-latency per FLOP halves, total weight-fetch instructions
// per launch halve (grid 1376 -> 688 blocks of 128 rows x 8 q-chunks).
// Per-row math bit-identical to R4 (same j-order, same chains, same
// wave-ascending reduce, same atomics) -> absmax must stay 0.001953125.
// No manual prefetch (register budget: ~36 xp + 36 acc + 40 weights + addr
// at (256,3)); #pragma unroll 2 lets the compiler pipeline loads.
// ---------------------------------------------------------------------------
__global__ __launch_bounds__(256, 3) void k_ffn(
    int layer, const float* __restrict__ x2g,
    const float* __restrict__ W1P, const float* __restrict__ W2P,
    float* __restrict__ Xn)
{
    __shared__ float Ls[4 * 128 * Dm];   // 36 KiB (final reduce only)

    const int tid  = threadIdx.x;
    const int lane = tid & 63;
    const int wv   = __builtin_amdgcn_readfirstlane(tid >> 6);
    const int rg   = blockIdx.x >> 3;     // 0..85 (128-row groups)
    const int q    = blockIdx.x & 7;      // 0..7
    const int row0 = rg * 128 + lane;
    const int row1 = row0 + 64;
    const int j0   = q * 256 + wv * 64;

    const v4f* w1p = (const v4f*)(W1P + ((size_t)layer * Dff + j0) * WROW);
    const v4f* w2p = (const v4f*)(W2P + ((size_t)layer * Dff + j0) * WROW);

    v2f xp0[9], xp1[9];
    #pragma unroll
    for (int k = 0; k < 9; k++) {
        xp0[k] = *(const v2f*)(x2g + (size_t)row0 * Dm + 2 * k);
        xp1[k] = *(const v2f*)(x2g + (size_t)row1 * Dm + 2 * k);
    }

    v2f acc0[9], acc1[9];
    #pragma unroll
    for (int k = 0; k < 9; k++) {
        acc0[k] = (v2f){0.f, 0.f};
        acc1[k] = (v2f){0.f, 0.f};
    }

    #pragma unroll 2
    for (int jj = 0; jj < 64; jj++) {
        const v4f a0 = w1p[jj * 5 + 0], a1 = w1p[jj * 5 + 1],
                  a2 = w1p[jj * 5 + 2], a3 = w1p[jj * 5 + 3],
                  a4 = w1p[jj * 5 + 4];
        const v4f c0 = w2p[jj * 5 + 0], c1 = w2p[jj * 5 + 1],
                  c2 = w2p[jj * 5 + 2], c3 = w2p[jj * 5 + 3],
                  c4 = w2p[jj * 5 + 4];

        // h for row0: two 9-term packed chains (even d in .x, odd d in .y)
        v2f h2a = xp0[0] * a0.lo;
        h2a = __builtin_elementwise_fma(xp0[1], a0.hi, h2a);
        h2a = __builtin_elementwise_fma(xp0[2], a1.lo, h2a);
        h2a = __builtin_elementwise_fma(xp0[3], a1.hi, h2a);
        h2a = __builtin_elementwise_fma(xp0[4], a2.lo, h2a);
        h2a = __builtin_elementwise_fma(xp0[5], a2.hi, h2a);
        h2a = __builtin_elementwise_fma(xp0[6], a3.lo, h2a);
        h2a = __builtin_elementwise_fma(xp0[7], a3.hi, h2a);
        h2a = __builtin_elementwise_fma(xp0[8], a4.lo, h2a);
        float ha = a4.z + h2a.x + h2a.y;           // b1 in slot 18
        ha = fmaxf(ha, 0.f);
        const v2f hha = {ha, ha};

        // h for row1 (same weight registers)
        v2f h2b = xp1[0] * a0.lo;
        h2b = __builtin_elementwise_fma(xp1[1], a0.hi, h2b);
        h2b = __builtin_elementwise_fma(xp1[2], a1.lo, h2b);
        h2b = __builtin_elementwise_fma(xp1[3], a1.hi, h2b);
        h2b = __builtin_elementwise_fma(xp1[4], a2.lo, h2b);
        h2b = __builtin_elementwise_fma(xp1[5], a2.hi, h2b);
        h2b = __builtin_elementwise_fma(xp1[6], a3.lo, h2b);
        h2b = __builtin_elementwise_fma(xp1[7], a3.hi, h2b);
        h2b = __builtin_elementwise_fma(xp1[8], a4.lo, h2b);
        float hb = a4.z + h2b.x + h2b.y;
        hb = fmaxf(hb, 0.f);
        const v2f hhb = {hb, hb};

        acc0[0] = __builtin_elementwise_fma(hha, c0.lo, acc0[0]);
        acc0[1] = __builtin_elementwise_fma(hha, c0.hi, acc0[1]);
        acc0[2] = __builtin_elementwise_fma(hha, c1.lo, acc0[2]);
        acc0[3] = __builtin_elementwise_fma(hha, c1.hi, acc0[3]);
        acc0[4] = __builtin_elementwise_fma(hha, c2.lo, acc0[4]);
        acc0[5] = __builtin_elementwise_fma(hha, c2.hi, acc0[5]);
        acc0[6] = __builtin_elementwise_fma(hha, c3.lo, acc0[6]);
        acc0[7] = __builtin_elementwise_fma(hha, c3.hi, acc0[7]);
        acc0[8] = __builtin_elementwise_fma(hha, c4.lo, acc0[8]);

        acc1[0] = __builtin_elementwise_fma(hhb, c0.lo, acc1[0]);
        acc1[1] = __builtin_elementwise_fma(hhb, c0.hi, acc1[1]);
        acc1[2] = __builtin_elementwise_fma(hhb, c1.lo, acc1[2]);
        acc1[3] = __builtin_elementwise_fma(hhb, c1.hi, acc1[3]);
        acc1[4] = __builtin_elementwise_fma(hhb, c2.lo, acc1[4]);
        acc1[5] = __builtin_elementwise_fma(hhb, c2.hi, acc1[5]);
        acc1[6] = __builtin_elementwise_fma(hhb, c3.lo, acc1[6]);
        acc1[7] = __builtin_elementwise_fma(hhb, c3.hi, acc1[7]);
        acc1[8] = __builtin_elementwise_fma(hhb, c4.lo, acc1[8]);
    }

    // ---- cross-wave reduce (layout [wave][row_in_128][18]) ----
    #pragma unroll
    for (int k = 0; k < 9; k++) {
        Ls[(wv * 128 + lane) * Dm + 2 * k]       = acc0[k].x;
        Ls[(wv * 128 + lane) * Dm + 2 * k + 1]   = acc0[k].y;
        Ls[(wv * 128 + lane + 64) * Dm + 2 * k]     = acc1[k].x;
        Ls[(wv * 128 + lane + 64) * Dm + 2 * k + 1] = acc1[k].y;
    }
    __syncthreads();
    for (int e = tid; e < 2304; e += 256) {
        float s = Ls[e] + Ls[2304 + e] + Ls[4608 + e] + Ls[6912 + e];
        unsafeAtomicAdd(&Xn[(size_t)rg * 2304 + e], s);
    }
}

// ---------------------------------------------------------------------------
// k_out: (i-chunk, batch) blocks; float4 stores of the 117 MB output.
// Final x is fully accumulated in xg (layer-5 k_ffn atomics) -> plain read.
// (UNCHANGED from R4)
// ---------------------------------------------------------------------------
__global__ __launch_bounds__(256) void k_out(
    const float* __restrict__ xg,
    const float* __restrict__ ll2W,
    const float* __restrict__ Mw, const float* __restrict__ PS1,
    const float* __restrict__ QS2, float* __restrict__ out)
{
    __shared__ float xb[Sq * Dm];
    __shared__ float M[602];
    __shared__ float T[2][Dm][Nb];
    __shared__ float Pc[32 * Nb];
    __shared__ float QBs[Am * Nb];

    const int b = blockIdx.y, chunk = blockIdx.x, tid = threadIdx.x;

    for (int e = tid; e < Sq * Dm; e += 256)
        xb[e] = xg[(size_t)b * (Sq * Dm) + e];
    for (int m = tid; m < 602; m += 256) M[m] = Mw[m];
    __syncthreads();

    for (int m = tid; m < 252; m += 256) {
        int half = m / 126, rem = m - half * 126;
        int d = rem / 7, n = rem - 7 * d;
        float a = 0.f;
        for (int s = 0; s < Sq; s++)
            a += xb[s * Dm + d] * M[half * 301 + s * 7 + n];
        T[half][d][n] = a;
    }
    __syncthreads();

    for (int m = tid; m < 224; m += 256) {
        int il = m / 7, n = m - 7 * il;
        int i = chunk * 32 + il;
        float a = PS1[i * 7 + n];
        #pragma unroll
        for (int d = 0; d < Dm; d++) a += T[0][d][n] * ll2W[d * Am + i];
        Pc[m] = a;
    }
    for (int e = tid; e < 896; e += 256) {
        int jj = e / 7, n = e - 7 * jj;
        float a = QS2[e];
        #pragma unroll
        for (int d = 0; d < Dm; d++) a += T[1][d][n] * ll2W[d * Am + jj];
        QBs[e] = a;
    }
    __syncthreads();

    if (tid < 224) {
        const int e = 4 * tid;
        const float q0 = QBs[e], q1 = QBs[e + 1], q2 = QBs[e + 2], q3 = QBs[e + 3];
        const int n0 = e % 7, n1 = (e + 1) % 7, n2 = (e + 2) % 7, n3 = (e + 3) % 7;
        const size_t base = (size_t)b * (Am * Am * Nb)
                          + (size_t)chunk * 32 * 896 + e;
        for (int il = 0; il < 32; il++) {
            const float* pc = Pc + il * 7;
            float4 v;
            v.x = pc[n0] + q0; v.y = pc[n1] + q1;
            v.z = pc[n2] + q2; v.w = pc[n3] + q3;
            *(float4*)(out + base + (size_t)il * 896) = v;
        }
    }
}

} // namespace

// ---------------------------------------------------------------------------
extern "C" void kernel_launch(void* const* d_in, const int* in_sizes, int n_in,
                              void* d_out, int out_size, void* d_ws, size_t ws_size,
                              hipStream_t stream)
{
    (void)in_sizes; (void)n_in; (void)out_size; (void)ws_size;

    const float* src  = (const float*)d_in[0];
    const int*   mask = (const int*)  d_in[1];
    const float* Wq   = (const float*)d_in[3];
    const float* bq   = (const float*)d_in[4];
    const float* Wk   = (const float*)d_in[5];
    const float* bk   = (const float*)d_in[6];
    const float* Wv   = (const float*)d_in[7];
    const float* bv   = (const float*)d_in[8];
    const float* Wo   = (const float*)d_in[9];
    const float* bo   = (const float*)d_in[10];
    const float* ln1a = (const float*)d_in[11];
    const float* ln1b = (const float*)d_in[12];
    const float* ln2a = (const float*)d_in[13];
    const float* ln2b = (const float*)d_in[14];
    const float* fW1  = (const float*)d_in[15];
    const float* fb1  = (const float*)d_in[16];
    const float* fW2  = (const float*)d_in[17];
    const float* fb2  = (const float*)d_in[18];
    const float* ll2W = (const float*)d_in[19];
    const float* ll2b = (const float*)d_in[20];
    const float* llW  = (const float*)d_in[21];
    const float* llb  = (const float*)d_in[22];
    const float* flW  = (const float*)d_in[23];
    const float* flb  = (const float*)d_in[24];
    float* out = (float*)d_out;

    const size_t WPSZ = (size_t)6 * Dff * WROW + WROW;   // 245780

    float* ws  = (float*)d_ws;
    float* xA  = ws;
    float* xB  = ws + 1 * (size_t)RSZ;
    float* x2g = ws + 2 * (size_t)RSZ;
    float* W1P = ws + 3 * (size_t)RSZ;
    float* W2P = W1P + WPSZ;
    float* Mw  = W2P + WPSZ;                  // 602 (pad 604)
    float* PS1 = Mw + 604;
    float* QS2 = PS1 + 896;                   // total ~4.4 MB

    for (int i = 0; i < 6; i++) {
        const float* Xi = (i == 0) ? src : ((i % 2 == 1) ? xB : xA);
        float*       Xn = (i % 2 == 0) ? xB : xA;
        const int nblk = (i == 0) ? 449 : 256;   // layer 0 carries prep blocks
        k_attn<<<nblk, 64, 0, stream>>>(i, Xi, Xn, x2g, mask,
                                        Wq, bq, Wk, bk, Wv, bv,
                                        ln1a, ln1b, Wo, bo, ln2a, ln2b, fb2,
                                        fW1, fb1, fW2, W1P, W2P,
                                        llW, llb, flW, flb, ll2b,
                                        Mw, PS1, QS2);
        k_ffn<<<688, 256, 0, stream>>>(i, x2g, W1P, W2P, Xn);
    }
    k_out<<<dim3(4, 256), 256, 0, stream>>>(xA, ll2W, Mw, PS1, QS2, out);
}

// Round 7
// 484.312 us; speedup vs baseline: 1.1549x; 1.0822x over previous
//
#include <hip/hip_runtime.h>
#include <math.h>

namespace {

constexpr int Sq = 43;
constexpr int Dm = 18;
constexpr int Dff = 2048;
constexpr int Am = 128;
constexpr int Nb = 7;
constexpr int NR = 11008;          // B*SEQ rows
constexpr int RSZ = NR * Dm;       // 198144 floats
constexpr int WROW = 20;           // padded weight row (18 w + b1 + pad)
constexpr float EPSf = 1e-6f;

typedef float v2f __attribute__((ext_vector_type(2)));
typedef float v4f __attribute__((ext_vector_type(4)));

// ---------------------------------------------------------------------------
// k_attn (R7): head-parallel. 192 threads = 3 waves; wave h owns head h.
//   Phase 1: every wave's lane q (<43) loads row, computes LN1 (redundant,
//            bit-identical) and ONLY its head's q/k/v 6-dim slices
//            (same dd-ascending chains as before -> identical bits).
//   Phase 2: wave h runs head-h attention (identical float2/expf chain,
//            same j order); stores normalized o6 to LDS.
//   Phase 3: wave 0 lanes do o-proj + residual + Xn seed + LN2 with the
//            unchanged dd-ascending chains reading identical values.
// Critical path ~3000 -> ~1400 FMA; 3 waves/CU instead of 1.
//   layer-0 extra blocks (grid 321):
//     256..319 : FFN weight prep (192-thread version).
//     320      : tail precompute (Mw / PS1 / QS2) for k_out.
// ---------------------------------------------------------------------------
__global__ __launch_bounds__(192) void k_attn(
    int layer,
    const float* __restrict__ Xi, float* __restrict__ Xn,
    float* __restrict__ x2g,
    const int* __restrict__ maskg,
    const float* __restrict__ Wq, const float* __restrict__ bq,
    const float* __restrict__ Wk, const float* __restrict__ bk,
    const float* __restrict__ Wv, const float* __restrict__ bv,
    const float* __restrict__ ln1a, const float* __restrict__ ln1b,
    const float* __restrict__ Wo, const float* __restrict__ bo,
    const float* __restrict__ ln2a, const float* __restrict__ ln2b,
    const float* __restrict__ b2g,
    const float* __restrict__ fW1g, const float* __restrict__ fb1g,
    const float* __restrict__ fW2g,
    float* __restrict__ W1P, float* __restrict__ W2P,
    const float* __restrict__ llW, const float* __restrict__ llb,
    const float* __restrict__ flW, const float* __restrict__ flb,
    const float* __restrict__ ll2b,
    float* __restrict__ Mw, float* __restrict__ PS1, float* __restrict__ QS2)
{
    __shared__ __align__(16) float ks[Sq * 20];
    __shared__ __align__(16) float vs[Sq * 20];
    __shared__ float os[Sq * Dm];
    __shared__ int ms[Sq];
    __shared__ float M[602];
    __shared__ float cc2[14];
    __shared__ float SS[14];

    const int tid = threadIdx.x;
    const int b = blockIdx.x;

    if (b >= 256) {                       // layer-0 auxiliary blocks only
        if (b < 320) {
            // ---- FFN weight prep (192-thread version) ----
            const int idx = (b - 256) * 192 + tid;     // 0..12287
            const int l = idx / Dff;
            const int j = idx - l * Dff;
            float* o1 = W1P + (size_t)idx * WROW;
            float* o2 = W2P + (size_t)idx * WROW;
            #pragma unroll
            for (int d = 0; d < Dm; d++)
                o1[d] = fW1g[(size_t)l * Dm * Dff + (size_t)d * Dff + j];
            o1[18] = fb1g[l * Dff + j];
            o1[19] = 0.f;
            #pragma unroll
            for (int d = 0; d < Dm; d++)
                o2[d] = fW2g[((size_t)l * Dff + j) * Dm + d];
            o2[18] = 0.f;
            o2[19] = 0.f;
            if (idx < WROW) {             // zero pad row (prefetch guard)
                W1P[(size_t)6 * Dff * WROW + idx] = 0.f;
                W2P[(size_t)6 * Dff * WROW + idx] = 0.f;
            }
            return;
        }
        // ---- b == 320: tail precompute (Mw / PS1 / QS2) ----
        for (int m = tid; m < 602; m += 192) {
            int half = m / 301, rem = m - half * 301;
            int s = rem / 7, n = rem - 7 * s;
            float a = 0.f;
            for (int jj = 0; jj < Am; jj++)
                a += llW[s * Am + jj] * flW[(half * Am + jj) * Nb + n];
            M[m] = a;
        }
        if (tid < 14) {
            int half = tid / 7, n = tid - 7 * (tid / 7);
            float a = 0.f;
            for (int jj = 0; jj < Am; jj++)
                a += llb[jj] * flW[(half * Am + jj) * Nb + n];
            cc2[tid] = a;
        }
        __syncthreads();
        if (tid < 14) {
            int half = tid / 7, n = tid - 7 * (tid / 7);
            float s2 = 0.f;
            for (int s = 0; s < Sq; s++) s2 += M[half * 301 + s * 7 + n];
            SS[tid] = s2;
        }
        __syncthreads();
        for (int m = tid; m < 602; m += 192) Mw[m] = M[m];
        for (int m = tid; m < 896; m += 192) {
            int i = m / 7, n = m - 7 * i;
            PS1[m] = cc2[n] + ll2b[i] * SS[n];
            QS2[m] = cc2[7 + n] + ll2b[i] * SS[7 + n] + flb[n];
        }
        return;
    }

    // -------------------- main path: one batch per block --------------------
    const float scale = 0.40824829046386296f;  // 1/sqrt(6)
    const int h = tid >> 6;        // wave id = head 0..2
    const int q = tid & 63;        // lane = query row

    if (tid < Sq) ms[tid] = maskg[b * Sq + tid];

    float y[Dm];
    float qv6[6];
    if (q < Sq) {
        const size_t ro = (size_t)(b * Sq + q) * Dm;
        // x row fully accumulated (prev layer's k_ffn atomics); float2 loads
        #pragma unroll
        for (int k = 0; k < 9; k++) {
            float2 t = *(const float2*)(Xi + ro + 2 * k);
            y[2 * k] = t.x; y[2 * k + 1] = t.y;
        }
        // LN1 (computed by all 3 waves redundantly -> identical bits)
        float mu = 0.f;
        #pragma unroll
        for (int d = 0; d < Dm; d++) mu += y[d];
        mu *= (1.f / Dm);
        float var = 0.f;
        #pragma unroll
        for (int d = 0; d < Dm; d++) { float t = y[d] - mu; var += t * t; }
        var *= (1.f / (Dm - 1));                 // ddof=1
        float isd = 1.f / (sqrtf(var) + EPSf);   // eps on sd
        float x2[Dm];
        #pragma unroll
        for (int d = 0; d < Dm; d++)
            x2[d] = ln1a[layer * Dm + d] * (y[d] - mu) * isd
                  + ln1b[layer * Dm + d];
        // q/k/v: ONLY this wave's head slice (d = h*6+dh), same chains
        const float* wqp = Wq + layer * Dm * Dm;
        const float* wkp = Wk + layer * Dm * Dm;
        const float* wvp = Wv + layer * Dm * Dm;
        #pragma unroll
        for (int dh = 0; dh < 6; dh++) {
            const int d = h * 6 + dh;
            float aq = bq[layer * Dm + d];
            float ak = bk[layer * Dm + d];
            float av = bv[layer * Dm + d];
            #pragma unroll
            for (int dd = 0; dd < Dm; dd++) {
                aq += x2[dd] * wqp[dd * Dm + d];
                ak += x2[dd] * wkp[dd * Dm + d];
                av += x2[dd] * wvp[dd * Dm + d];
            }
            qv6[dh] = aq;
            ks[q * 20 + d] = ak;
            vs[q * 20 + d] = av;
        }
    }
    __syncthreads();

    // phase 2: this wave's head attention (identical chain & j-order)
    if (q < Sq) {
        float sum = 0.f;
        float o6[6];
        #pragma unroll
        for (int d = 0; d < 6; d++) o6[d] = 0.f;
        const float q0 = qv6[0], q1 = qv6[1], q2 = qv6[2];
        const float q3 = qv6[3], q4 = qv6[4], q5 = qv6[5];
        for (int j = 0; j < Sq; j++) {
            const float* kr = ks + j * 20 + h * 6;   // 8B-aligned (h*6 even)
            const float2 k0 = *(const float2*)(kr);
            const float2 k1 = *(const float2*)(kr + 2);
            const float2 k2 = *(const float2*)(kr + 4);
            float t = q0 * k0.x + q1 * k0.y + q2 * k1.x +
                      q3 * k1.y + q4 * k2.x + q5 * k2.y;
            t *= scale;
            if (ms[j] == 0) t = -1e9f;
            float e = __expf(t);
            sum += e;
            const float* vr = vs + j * 20 + h * 6;
            const float2 v0 = *(const float2*)(vr);
            const float2 v1 = *(const float2*)(vr + 2);
            const float2 v2 = *(const float2*)(vr + 4);
            o6[0] += e * v0.x; o6[1] += e * v0.y; o6[2] += e * v1.x;
            o6[3] += e * v1.y; o6[4] += e * v2.x; o6[5] += e * v2.y;
        }
        float inv = 1.f / sum;
        #pragma unroll
        for (int d = 0; d < 6; d++) os[q * Dm + h * 6 + d] = o6[d] * inv;
    }
    __syncthreads();

    // phase 3: wave 0 -> o-proj + residual + next-x seed + LN2 (same chains)
    if (h == 0 && q < Sq) {
        const float* wo = Wo + layer * Dm * Dm;
        const float* orow = os + q * Dm;
        float yo[Dm];
        #pragma unroll 3
        for (int d = 0; d < Dm; d++) {
            float t = bo[layer * Dm + d];
            #pragma unroll
            for (int dd = 0; dd < Dm; dd++) t += orow[dd] * wo[dd * Dm + d];
            yo[d] = y[d] + t;
        }
        const size_t ro = (size_t)(b * Sq + q) * Dm;
        #pragma unroll
        for (int d = 0; d < Dm; d++)
            Xn[ro + d] = yo[d] + b2g[layer * Dm + d];  // seed: FFN atomics add
        float mu = 0.f;
        #pragma unroll
        for (int d = 0; d < Dm; d++) mu += yo[d];
        mu *= (1.f / Dm);
        float var = 0.f;
        #pragma unroll
        for (int d = 0; d < Dm; d++) { float t = yo[d] - mu; var += t * t; }
        var *= (1.f / (Dm - 1));
        float isd = 1.f / (sqrtf(var) + EPSf);
        #pragma unroll
        for (int d = 0; d < Dm; d++)
            x2g[ro + d] =
                ln2a[layer * Dm + d] * (yo[d] - mu) * isd + ln2b[layer * Dm + d];
    }
}

// ---------------------------------------------------------------------------
// k_ffn: R4 verbatim (confirmed local optimum). Packed fp32 via compiler
// ISel, 1376 blocks = 172 rg x 8 jc, 4 waves, 1-deep register prefetch,
// atomic accumulate into Xn (seeded by k_attn with y+b2).
// ---------------------------------------------------------------------------
__global__ __launch_bounds__(256, 3) void k_ffn(
    int layer, const float* __restrict__ x2g,
    const float* __restrict__ W1P, const float* __restrict__ W2P,
    float* __restrict__ Xn)
{
    __shared__ float Ls[4 * 64 * Dm];   // 18 KiB (final reduce only)

    const int tid  = threadIdx.x;
    const int lane = tid & 63;
    const int wv   = __builtin_amdgcn_readfirstlane(tid >> 6);
    const int rg   = blockIdx.x >> 3;     // 0..171
    const int q    = blockIdx.x & 7;      // 0..7
    const int row  = rg * 64 + lane;
    const int j0   = q * 256 + wv * 64;

    const v4f* w1p = (const v4f*)(W1P + ((size_t)layer * Dff + j0) * WROW);
    const v4f* w2p = (const v4f*)(W2P + ((size_t)layer * Dff + j0) * WROW);

    v2f xp[9];
    #pragma unroll
    for (int k = 0; k < 9; k++)
        xp[k] = *(const v2f*)(x2g + (size_t)row * Dm + 2 * k);

    v2f acc2[9];
    #pragma unroll
    for (int k = 0; k < 9; k++) acc2[k] = (v2f){0.f, 0.f};

    v4f a0 = w1p[0], a1 = w1p[1], a2 = w1p[2], a3 = w1p[3], a4 = w1p[4];
    v4f c0 = w2p[0], c1 = w2p[1], c2 = w2p[2], c3 = w2p[3], c4 = w2p[4];

    for (int jj = 0; jj < 64; jj++) {
        const v4f* n1 = w1p + (jj + 1) * 5;        // pad row guards j=2048
        const v4f* n2 = w2p + (jj + 1) * 5;
        const v4f na0 = n1[0], na1 = n1[1], na2 = n1[2], na3 = n1[3], na4 = n1[4];
        const v4f nc0 = n2[0], nc1 = n2[1], nc2 = n2[2], nc3 = n2[3], nc4 = n2[4];

        // h: two 9-term packed chains (even d in .x, odd d in .y)
        v2f h2 = xp[0] * a0.lo;
        h2 = __builtin_elementwise_fma(xp[1], a0.hi, h2);
        h2 = __builtin_elementwise_fma(xp[2], a1.lo, h2);
        h2 = __builtin_elementwise_fma(xp[3], a1.hi, h2);
        h2 = __builtin_elementwise_fma(xp[4], a2.lo, h2);
        h2 = __builtin_elementwise_fma(xp[5], a2.hi, h2);
        h2 = __builtin_elementwise_fma(xp[6], a3.lo, h2);
        h2 = __builtin_elementwise_fma(xp[7], a3.hi, h2);
        h2 = __builtin_elementwise_fma(xp[8], a4.lo, h2);
        float h = a4.z + h2.x + h2.y;              // b1 in slot 18
        h = fmaxf(h, 0.f);
        const v2f hh = {h, h};

        acc2[0] = __builtin_elementwise_fma(hh, c0.lo, acc2[0]);
        acc2[1] = __builtin_elementwise_fma(hh, c0.hi, acc2[1]);
        acc2[2] = __builtin_elementwise_fma(hh, c1.lo, acc2[2]);
        acc2[3] = __builtin_elementwise_fma(hh, c1.hi, acc2[3]);
        acc2[4] = __builtin_elementwise_fma(hh, c2.lo, acc2[4]);
        acc2[5] = __builtin_elementwise_fma(hh, c2.hi, acc2[5]);
        acc2[6] = __builtin_elementwise_fma(hh, c3.lo, acc2[6]);
        acc2[7] = __builtin_elementwise_fma(hh, c3.hi, acc2[7]);
        acc2[8] = __builtin_elementwise_fma(hh, c4.lo, acc2[8]);

        a0 = na0; a1 = na1; a2 = na2; a3 = na3; a4 = na4;
        c0 = nc0; c1 = nc1; c2 = nc2; c3 = nc3; c4 = nc4;
    }

    #pragma unroll
    for (int k = 0; k < 9; k++) {
        Ls[(wv * 64 + lane) * Dm + 2 * k]     = acc2[k].x;
        Ls[(wv * 64 + lane) * Dm + 2 * k + 1] = acc2[k].y;
    }
    __syncthreads();
    for (int e = tid; e < 1152; e += 256) {
        float s = Ls[e] + Ls[1152 + e] + Ls[2304 + e] + Ls[3456 + e];
        unsafeAtomicAdd(&Xn[(size_t)rg * 1152 + e], s);
    }
}

// ---------------------------------------------------------------------------
// k_out: (i-chunk, batch) blocks; float4 stores of the 117 MB output.
// Final x is fully accumulated in xg (layer-5 k_ffn atomics) -> plain read.
// (UNCHANGED)
// ---------------------------------------------------------------------------
__global__ __launch_bounds__(256) void k_out(
    const float* __restrict__ xg,
    const float* __restrict__ ll2W,
    const float* __restrict__ Mw, const float* __restrict__ PS1,
    const float* __restrict__ QS2, float* __restrict__ out)
{
    __shared__ float xb[Sq * Dm];
    __shared__ float M[602];
    __shared__ float T[2][Dm][Nb];
    __shared__ float Pc[32 * Nb];
    __shared__ float QBs[Am * Nb];

    const int b = blockIdx.y, chunk = blockIdx.x, tid = threadIdx.x;

    for (int e = tid; e < Sq * Dm; e += 256)
        xb[e] = xg[(size_t)b * (Sq * Dm) + e];
    for (int m = tid; m < 602; m += 256) M[m] = Mw[m];
    __syncthreads();

    for (int m = tid; m < 252; m += 256) {
        int half = m / 126, rem = m - half * 126;
        int d = rem / 7, n = rem - 7 * d;
        float a = 0.f;
        for (int s = 0; s < Sq; s++)
            a += xb[s * Dm + d] * M[half * 301 + s * 7 + n];
        T[half][d][n] = a;
    }
    __syncthreads();

    for (int m = tid; m < 224; m += 256) {
        int il = m / 7, n = m - 7 * il;
        int i = chunk * 32 + il;
        float a = PS1[i * 7 + n];
        #pragma unroll
        for (int d = 0; d < Dm; d++) a += T[0][d][n] * ll2W[d * Am + i];
        Pc[m] = a;
    }
    for (int e = tid; e < 896; e += 256) {
        int jj = e / 7, n = e - 7 * jj;
        float a = QS2[e];
        #pragma unroll
        for (int d = 0; d < Dm; d++) a += T[1][d][n] * ll2W[d * Am + jj];
        QBs[e] = a;
    }
    __syncthreads();

    if (tid < 224) {
        const int e = 4 * tid;
        const float q0 = QBs[e], q1 = QBs[e + 1], q2 = QBs[e + 2], q3 = QBs[e + 3];
        const int n0 = e % 7, n1 = (e + 1) % 7, n2 = (e + 2) % 7, n3 = (e + 3) % 7;
        const size_t base = (size_t)b * (Am * Am * Nb)
                          + (size_t)chunk * 32 * 896 + e;
        for (int il = 0; il < 32; il++) {
            const float* pc = Pc + il * 7;
            float4 v;
            v.x = pc[n0] + q0; v.y = pc[n1] + q1;
            v.z = pc[n2] + q2; v.w = pc[n3] + q3;
            *(float4*)(out + base + (size_t)il * 896) = v;
        }
    }
}

} // namespace

// ---------------------------------------------------------------------------
extern "C" void kernel_launch(void* const* d_in, const int* in_sizes, int n_in,
                              void* d_out, int out_size, void* d_ws, size_t ws_size,
                              hipStream_t stream)
{
    (void)in_sizes; (void)n_in; (void)out_size; (void)ws_size;

    const float* src  = (const float*)d_in[0];
    const int*   mask = (const int*)  d_in[1];
    const float* Wq   = (const float*)d_in[3];
    const float* bq   = (const float*)d_in[4];
    const float* Wk   = (const float*)d_in[5];
    const float* bk   = (const float*)d_in[6];
    const float* Wv   = (const float*)d_in[7];
    const float* bv   = (const float*)d_in[8];
    const float* Wo   = (const float*)d_in[9];
    const float* bo   = (const float*)d_in[10];
    const float* ln1a = (const float*)d_in[11];
    const float* ln1b = (const float*)d_in[12];
    const float* ln2a = (const float*)d_in[13];
    const float* ln2b = (const float*)d_in[14];
    const float* fW1  = (const float*)d_in[15];
    const float* fb1  = (const float*)d_in[16];
    const float* fW2  = (const float*)d_in[17];
    const float* fb2  = (const float*)d_in[18];
    const float* ll2W = (const float*)d_in[19];
    const float* ll2b = (const float*)d_in[20];
    const float* llW  = (const float*)d_in[21];
    const float* llb  = (const float*)d_in[22];
    const float* flW  = (const float*)d_in[23];
    const float* flb  = (const float*)d_in[24];
    float* out = (float*)d_out;

    const size_t WPSZ = (size_t)6 * Dff * WROW + WROW;   // 245780

    float* ws  = (float*)d_ws;
    float* xA  = ws;
    float* xB  = ws + 1 * (size_t)RSZ;
    float* x2g = ws + 2 * (size_t)RSZ;
    float* W1P = ws + 3 * (size_t)RSZ;
    float* W2P = W1P + WPSZ;
    float* Mw  = W2P + WPSZ;                  // 602 (pad 604)
    float* PS1 = Mw + 604;
    float* QS2 = PS1 + 896;                   // total ~4.4 MB

    for (int i = 0; i < 6; i++) {
        const float* Xi = (i == 0) ? src : ((i % 2 == 1) ? xB : xA);
        float*       Xn = (i % 2 == 0) ? xB : xA;
        const int nblk = (i == 0) ? 321 : 256;   // layer 0 carries prep blocks
        k_attn<<<nblk, 192, 0, stream>>>(i, Xi, Xn, x2g, mask,
                                         Wq, bq, Wk, bk, Wv, bv,
                                         ln1a, ln1b, Wo, bo, ln2a, ln2b, fb2,
                                         fW1, fb1, fW2, W1P, W2P,
                                         llW, llb, flW, flb, ll2b,
                                         Mw, PS1, QS2);
        k_ffn<<<1376, 256, 0, stream>>>(i, x2g, W1P, W2P, Xn);
    }
    k_out<<<dim3(4, 256), 256, 0, stream>>>(xA, ll2W, Mw, PS1, QS2, out);
}